// Round 5
// baseline (8429.460 us; speedup 1.0000x reference)
//
#include <hip/hip_runtime.h>
#include <cstdint>
#include <cstddef>

#define T_ 256
#define B_ 128
#define E_ 512
#define H_ 1024
#define BH (B_*H_)
#define PP 2056   // panel pitch in halves: 2048+8 -> row stride 4112B (16B-aligned, 2-way bank alias only)

typedef _Float16 v8h __attribute__((ext_vector_type(8)));
typedef float    v4f __attribute__((ext_vector_type(4)));
typedef unsigned int u32x4 __attribute__((ext_vector_type(4)));

__device__ __forceinline__ float sigmoidf_(float x) {
    return 1.0f / (1.0f + __expf(-x));
}
__device__ __forceinline__ float tanhf_(float x) {
    // tanh(x) = 1 - 2/(exp(2x)+1); saturates correctly at +/-inf
    return 1.0f - 2.0f / (__expf(2.0f * x) + 1.0f);
}

// --- agent-coherent (cross-XCD) accessors: bypass L1/L2 so readers on other
// XCDs always see fresh data without cache-invalidates (which would evict
// the L2-warm weights). Only the mutable h-state uses these.
__device__ __forceinline__ u32x4 sc_load16(const void* p) {
    u32x4 v;
    asm volatile("global_load_dwordx4 %0, %1, off sc0 sc1"
                 : "=v"(v) : "v"(p) : "memory");
    return v;
}
__device__ __forceinline__ void sc_store16(void* p, u32x4 v) {
    asm volatile("global_store_dwordx4 %0, %1, off sc0 sc1"
                 :: "v"(p), "v"(v) : "memory");
}
__device__ __forceinline__ void sc_store2(void* p, unsigned v) {
    asm volatile("global_store_short %0, %1, off sc0 sc1"
                 :: "v"(p), "v"(v) : "memory");
}
#define VMCNT0() asm volatile("s_waitcnt vmcnt(0)" ::: "memory")

// ---------------------------------------------------------------------------
// Persistent fused GRU, R5:
//  * barrier-free chunk loop: MFMA B-fragments loaded DIRECTLY from global
//    (weights L2/L1-warm; per-lane v8h addresses replicate the old Blds
//    layout exactly) -> no per-chunk __syncthreads / vmcnt(0) drains; the
//    compiler pipelines chunk kc+1 loads under chunk kc MFMAs.
//  * LDS holds only the A-panel ([x|h] or [hn0|h] row-block), prefetched
//    once per iteration with a single vmcnt(0) drain.
//  * per-rtile-group barriers (64 WGs each): the 4 batch-row groups are
//    fully independent (GRU rows don't interact), so no global barrier.
// WG = 32 rows x 32 hidden cols (96 gate cols), 4 waves, 1 WG/CU.
// ---------------------------------------------------------------------------
template<int PHASE>
__device__ __forceinline__ void run_phase(
    const int* __restrict__ bs,
    const _Float16* __restrict__ x16,
    const _Float16* __restrict__ Wseg0,   // phase0: Wi0[3072][512], phase1: Wi1[3072][1024]
    const _Float16* __restrict__ Wseg1,   // Wh (always [3072][1024])
    const float* __restrict__ bb,         // bias block for this phase [4][1024]
    float* __restrict__ hf,               // fp32 master (WG-private rows)
    _Float16* __restrict__ hh,            // fp16 shadow x2 (ping-pong)
    _Float16* __restrict__ hn0,           // layer0 out x2
    int* __restrict__ barctr,
    _Float16 (&Pan)[32][PP],
    int rtile, int jtile)
{
    const int tid = threadIdx.x;
    const int lane = tid & 63, w = tid >> 6;
    const int rh = w & 1, hq = w >> 1;
    const int m = lane & 15, q = lane >> 4;
    const int prow = tid >> 3, pslot = tid & 7;
    const int colG = jtile + hq * 16 + m;

    constexpr int K0 = PHASE ? 16 : 8;     // seg0 chunks (x/hn0 part)
    constexpr int NU = PHASE ? 32 : 24;    // panel 16B-units per thread
    constexpr int J0 = PHASE ? 16 : 8;     // units from seg0 source
    const int bp0 = PHASE ? H_ : E_;

    const float br = bb[colG];
    const float bz = bb[H_ + colG];
    const float bi = bb[2 * H_ + colG];
    const float bh = bb[3 * H_ + colG];

    // weight fragment base pointers (per-lane, colG folded in)
    const _Float16* B0r = Wseg0 + (size_t)colG * bp0;
    const _Float16* B0z = B0r + (size_t)H_ * bp0;
    const _Float16* B0n = B0z + (size_t)H_ * bp0;
    const _Float16* B1r = Wseg1 + (size_t)colG * H_;
    const _Float16* B1z = B1r + (size_t)H_ * H_;
    const _Float16* B1n = B1z + (size_t)H_ * H_;

    // per-group barrier: group = rtile block; 8 shard lines, 8 arrivals each
    int* gctr = barctr + (rtile >> 5) * (8 * 64);
    const int myshard = (jtile >> 5) & 7;

    for (int k = 0; k <= T_; ++k) {
        const bool active = PHASE ? (k > 0) : (k < T_);
        int bs_t = 0, pr = 0;
        const _Float16* hh_r = nullptr;
        _Float16* hh_w = nullptr;
        if (active) {
            const int t = PHASE ? (k - 1) : k;
            bs_t = bs[t];
            pr = t & 1;
            const int pw = (t + 1) & 1;
            hh_r = hh + (size_t)pr * BH;
            hh_w = hh + (size_t)pw * BH;

            if (rtile >= bs_t) {
                // inactive tile: keep ping-pong coherent (agent scope)
                if (tid < 128) {
                    int r = tid >> 2, cc = tid & 3;
                    size_t off = (size_t)(rtile + r) * H_ + jtile + cc * 8;
                    u32x4 v = sc_load16(hh_r + off);
                    VMCNT0();
                    sc_store16(hh_w + off, v);
                }
            } else {
                // ---- A-panel prefetch: issue ALL, drain once, write LDS ----
                const _Float16* s0 = PHASE
                    ? (hn0 + (size_t)pr * BH + (size_t)(rtile + prow) * H_)
                    : (x16 + (size_t)t * B_ * E_ + (size_t)(rtile + prow) * E_);
                const _Float16* s1 = hh_r + (size_t)(rtile + prow) * H_;
                u32x4 v[NU];
#pragma unroll
                for (int j = 0; j < NU; ++j) {
                    int u = pslot + j * 8;
                    if (j < J0) {
                        const _Float16* p = s0 + u * 8;
                        if (PHASE) v[j] = sc_load16(p);       // hn0: cross-XCD
                        else       v[j] = *(const u32x4*)p;   // x: read-only cached
                    } else {
                        v[j] = sc_load16(s1 + (u - J0 * 8) * 8);  // h: cross-XCD
                    }
                }
                VMCNT0();
#pragma unroll
                for (int j = 0; j < NU; ++j) {
                    int u = pslot + j * 8;
                    *(u32x4*)&Pan[prow][u * 8] = v[j];
                }
            }
        }
        __syncthreads();   // panel ready (uniform per WG)

        if (active && rtile < bs_t) {
            const v4f vz = {0.f, 0.f, 0.f, 0.f};
            v4f acc0 = vz, acc1 = vz, acc2 = vz, acc3 = vz;
            const _Float16* arow = &Pan[rh * 16 + m][0];

            // ---- seg0: x@Wi (phase0) / hn0@Wi1 (phase1); no barriers ----
#pragma unroll 4
            for (int kc = 0; kc < K0; ++kc) {
#pragma unroll
                for (int s = 0; s < 2; ++s) {
                    const int o = kc * 64 + s * 32 + q * 8;
                    v8h a  = *(const v8h*)(arow + o);
                    v8h b0 = *(const v8h*)(B0r + o);
                    v8h b1 = *(const v8h*)(B0z + o);
                    v8h b2 = *(const v8h*)(B0n + o);
                    acc0 = __builtin_amdgcn_mfma_f32_16x16x32_f16(a, b0, acc0, 0, 0, 0);
                    acc1 = __builtin_amdgcn_mfma_f32_16x16x32_f16(a, b1, acc1, 0, 0, 0);
                    acc2 = __builtin_amdgcn_mfma_f32_16x16x32_f16(a, b2, acc2, 0, 0, 0);
                }
            }
            // ---- seg1: h@Wh ----
#pragma unroll 4
            for (int kc = 0; kc < 16; ++kc) {
#pragma unroll
                for (int s = 0; s < 2; ++s) {
                    const int o = kc * 64 + s * 32 + q * 8;
                    v8h a  = *(const v8h*)(arow + K0 * 64 + o);
                    v8h b0 = *(const v8h*)(B1r + o);
                    v8h b1 = *(const v8h*)(B1z + o);
                    v8h b2 = *(const v8h*)(B1n + o);
                    acc0 = __builtin_amdgcn_mfma_f32_16x16x32_f16(a, b0, acc0, 0, 0, 0);
                    acc1 = __builtin_amdgcn_mfma_f32_16x16x32_f16(a, b1, acc1, 0, 0, 0);
                    acc3 = __builtin_amdgcn_mfma_f32_16x16x32_f16(a, b2, acc3, 0, 0, 0);
                }
            }

            // ---- epilogue. C/D layout: col = lane&15, row = quad*4 + reg ----
            _Float16* hn0w = hn0 + (size_t)pr * BH;   // phase0 writes hn0[t&1]
#pragma unroll
            for (int reg = 0; reg < 4; ++reg) {
                int rowG = rtile + rh * 16 + q * 4 + reg;
                size_t off = (size_t)rowG * H_ + colG;
                float hprev = hf[off];
                float rr = sigmoidf_(acc0[reg] + br);
                float zz = sigmoidf_(acc1[reg] + bz);
                float nn = tanhf_(acc2[reg] + bi + rr * (acc3[reg] + bh));
                float hnew = (1.0f - zz) * nn + zz * hprev;
                bool act = rowG < bs_t;
                float hsel = act ? hnew : hprev;
                if (PHASE == 0)   // layer1 input: unmasked hn
                    sc_store2(hn0w + off, (unsigned)__builtin_bit_cast(unsigned short, (_Float16)hnew));
                sc_store2(hh_w + off, (unsigned)__builtin_bit_cast(unsigned short, (_Float16)hsel));
                if (act) hf[off] = hnew;   // WG-private fp32 master: cached
            }
        }

        // ---- per-group barrier (64 WGs; no L2 invalidate) ----
        if (k < T_) {
            VMCNT0();            // drain this wave's sc-stores
            __syncthreads();     // whole WG done
            if (tid == 0) {
                __hip_atomic_fetch_add(gctr + myshard * 64, 1,
                                       __ATOMIC_RELEASE, __HIP_MEMORY_SCOPE_AGENT);
                const int target = 64 * (k + 1);
                for (;;) {
                    int ssum = 0;
#pragma unroll
                    for (int i = 0; i < 8; ++i)
                        ssum += __hip_atomic_load(gctr + i * 64,
                                                  __ATOMIC_RELAXED, __HIP_MEMORY_SCOPE_AGENT);
                    if (ssum >= target) break;
                    __builtin_amdgcn_s_sleep(1);
                }
            }
            __syncthreads();
        }
    }
}

__global__ __launch_bounds__(256, 1) void gru_persist(
    const int* __restrict__ bs,
    const _Float16* __restrict__ x16,
    const _Float16* __restrict__ Wi0,
    const _Float16* __restrict__ Wh0,
    const _Float16* __restrict__ Wi1,
    const _Float16* __restrict__ Wh1,
    const float* __restrict__ bias,
    float* __restrict__ h0f, float* __restrict__ h1f,
    _Float16* __restrict__ h0h, _Float16* __restrict__ h1h,
    _Float16* __restrict__ hn0,
    int* __restrict__ barctr)
{
    __shared__ _Float16 Pan[32][PP];     // 131,584 B
    const int rtile = blockIdx.y * 32;
    const int jtile = blockIdx.x * 32;
    if (blockIdx.z == 0)
        run_phase<0>(bs, x16, Wi0, Wh0, bias,          h0f, h0h, hn0, barctr, Pan, rtile, jtile);
    else
        run_phase<1>(bs, x16, Wi1, Wh1, bias + 4 * H_, h1f, h1h, hn0, barctr, Pan, rtile, jtile);
}

// ---------------------------------------------------------------------------
// Preamble / epilogue helpers
// ---------------------------------------------------------------------------
__global__ void cvt_f32_f16(const float* __restrict__ s, _Float16* __restrict__ d, int n) {
    int i = (blockIdx.x * 256 + threadIdx.x) * 8;
    if (i >= n) return;
    float4 v0 = *(const float4*)(s + i);
    float4 v1 = *(const float4*)(s + i + 4);
    v8h o = { (_Float16)v0.x, (_Float16)v0.y, (_Float16)v0.z, (_Float16)v0.w,
              (_Float16)v1.x, (_Float16)v1.y, (_Float16)v1.z, (_Float16)v1.w };
    *(v8h*)(d + i) = o;
}

__global__ void prep_bias(const float* __restrict__ bi0, const float* __restrict__ bh0,
                          const float* __restrict__ bi1, const float* __restrict__ bh1,
                          float* __restrict__ bias) {
    int tid = blockIdx.x * 256 + threadIdx.x;   // 2048 threads
    int l = tid >> 10, j = tid & 1023;
    const float* bi = l ? bi1 : bi0;
    const float* bh = l ? bh1 : bh0;
    float* o = bias + l * 4 * H_;
    o[j]           = bi[j] + bh[j];              // r gate combined
    o[H_ + j]      = bi[H_ + j] + bh[H_ + j];    // z gate combined
    o[2 * H_ + j]  = bi[2 * H_ + j];             // n gate, input part
    o[3 * H_ + j]  = bh[2 * H_ + j];             // n gate, hidden part
}

__global__ void gather_out(const float* __restrict__ h0f, const float* __restrict__ h1f,
                           const int* __restrict__ unsorted, float* __restrict__ out) {
    int rowid = blockIdx.x;          // 256 = L*B
    int l = rowid >> 7, b = rowid & 127;
    int src = unsorted[b];
    const float* s = (l ? h1f : h0f) + (size_t)src * H_;
    float* o = out + (size_t)rowid * H_;
    int c = threadIdx.x * 4;
    *(float4*)(o + c) = *(const float4*)(s + c);
}

// ---------------------------------------------------------------------------
extern "C" void kernel_launch(void* const* d_in, const int* in_sizes, int n_in,
                              void* d_out, int out_size, void* d_ws, size_t ws_size,
                              hipStream_t stream) {
    const float* x    = (const float*)d_in[0];
    const float* Wi0f = (const float*)d_in[1];
    const float* Wh0f = (const float*)d_in[2];
    const float* bi0  = (const float*)d_in[3];
    const float* bh0  = (const float*)d_in[4];
    const float* Wi1f = (const float*)d_in[5];
    const float* Wh1f = (const float*)d_in[6];
    const float* bi1  = (const float*)d_in[7];
    const float* bh1  = (const float*)d_in[8];
    const int*  bs       = (const int*)d_in[9];
    const int*  unsorted = (const int*)d_in[10];
    float* out = (float*)d_out;

    char* ws = (char*)d_ws;
    size_t off = 0;
    auto alloc = [&](size_t bytes) -> char* {
        char* p = ws + off;
        off += (bytes + 255) & ~(size_t)255;
        return p;
    };
    _Float16* x16 = (_Float16*)alloc((size_t)T_ * B_ * E_ * 2);
    _Float16* Wi0 = (_Float16*)alloc((size_t)3 * H_ * E_ * 2);
    _Float16* Wh0 = (_Float16*)alloc((size_t)3 * H_ * H_ * 2);
    _Float16* Wi1 = (_Float16*)alloc((size_t)3 * H_ * H_ * 2);
    _Float16* Wh1 = (_Float16*)alloc((size_t)3 * H_ * H_ * 2);
    float*    bias = (float*)alloc(2 * 4 * H_ * 4);
    char* zbase = ws + off;                  // zero-init block start
    float*    h0f = (float*)alloc((size_t)BH * 4);
    float*    h1f = (float*)alloc((size_t)BH * 4);
    _Float16* h0h = (_Float16*)alloc((size_t)2 * BH * 2);
    _Float16* h1h = (_Float16*)alloc((size_t)2 * BH * 2);
    _Float16* hn0 = (_Float16*)alloc((size_t)2 * BH * 2);
    int*      barctr = (int*)alloc(4 * 8 * 256);   // 4 groups x 8 shard lines
    size_t zbytes = (size_t)((ws + off) - zbase);

    // h states (fp32 masters + fp16 shadows) + barrier block start at zero.
    (void)hipMemsetAsync(zbase, 0, zbytes, stream);

    cvt_f32_f16<<<(T_ * B_ * E_) / 2048, 256, 0, stream>>>(x, x16, T_ * B_ * E_);
    cvt_f32_f16<<<(3 * H_ * E_) / 2048, 256, 0, stream>>>(Wi0f, Wi0, 3 * H_ * E_);
    cvt_f32_f16<<<(3 * H_ * H_) / 2048, 256, 0, stream>>>(Wh0f, Wh0, 3 * H_ * H_);
    cvt_f32_f16<<<(3 * H_ * H_) / 2048, 256, 0, stream>>>(Wi1f, Wi1, 3 * H_ * H_);
    cvt_f32_f16<<<(3 * H_ * H_) / 2048, 256, 0, stream>>>(Wh1f, Wh1, 3 * H_ * H_);
    prep_bias<<<8, 256, 0, stream>>>(bi0, bh0, bi1, bh1, bias);

    // Persistent: 256 WGs on 256 CUs (128.5 KiB LDS -> exactly 1 WG/CU,
    // all co-resident; per-group spin barriers are safe).
    dim3 grid(H_ / 32, B_ / 32, 2);
    gru_persist<<<grid, 256, 0, stream>>>(bs, x16, Wi0, Wh0, Wi1, Wh1, bias,
                                          h0f, h1f, h0h, h1h, hn0, barctr);
    gather_out<<<256, 256, 0, stream>>>(h0f, h1f, unsorted, out);
}

// Round 6
// 5884.796 us; speedup vs baseline: 1.4324x; 1.4324x over previous
//
#include <hip/hip_runtime.h>
#include <cstdint>
#include <cstddef>

#define T_ 256
#define B_ 128
#define E_ 512
#define H_ 1024
#define BH (B_*H_)
#define GI (B_*3072)      // one gi buffer (fp32): 128 x 3072
#define NWG 256

typedef _Float16 v8h __attribute__((ext_vector_type(8)));
typedef float    v4f __attribute__((ext_vector_type(4)));
typedef unsigned int u32x4 __attribute__((ext_vector_type(4)));

__device__ __forceinline__ float sigmoidf_(float x) {
    return 1.0f / (1.0f + __expf(-x));
}
__device__ __forceinline__ float tanhf_(float x) {
    return 1.0f - 2.0f / (__expf(2.0f * x) + 1.0f);
}

// Cross-WG data is WRITTEN with L1/L2-bypassing stores (small volume), and
// READ with normal cached loads; read coherence comes from the acquire-inv
// at the barrier. Weights live in LDS, so the invalidate costs nothing.
__device__ __forceinline__ void sc_store2(void* p, unsigned v) {
    asm volatile("global_store_short %0, %1, off sc0 sc1" :: "v"(p), "v"(v) : "memory");
}
__device__ __forceinline__ void sc_store4(void* p, float v) {
    asm volatile("global_store_dword %0, %1, off sc0 sc1" :: "v"(p), "v"(v) : "memory");
}

// ---------------------------------------------------------------------------
// Persistent 4-stage pipelined GRU. 256 WGs (1/CU, LDS-bound), 259 iterations.
// Iteration k:
//   D (wg 0..63):    gi0[t=k]   = x[t] @ Wi0.T          (k <= T-1)
//   A (wg 64..127):  h0/hn0[t=k-1] from gi0[t] + h0@Wh0 (1 <= k <= T)
//   C (wg 128..191): gi1[t=k-2] = hn0[t] @ Wi1.T        (2 <= k <= T+1)
//   B (wg 192..255): h1[t=k-3] from gi1[t] + h1@Wh1     (3 <= k <= T+2)
// Every stage-t datum lives in ping-pong buffer (t&1); consumers run exactly
// one iteration after producers -> barrier-separated, never same-buffer.
// Per WG: 48 gate cols (=16 hidden cols x 3 gates for A/B) x K<=1024 weight
// slice resident in LDS (<=110 KB). A-panel staged per 64-half chunk, dbuf.
// ---------------------------------------------------------------------------
__global__ __launch_bounds__(256, 1) void gru_persist(
    const int* __restrict__ bs,
    const _Float16* __restrict__ x16,   // [T][B][E]
    const _Float16* __restrict__ Wi0,   // [3072][512]
    const _Float16* __restrict__ Wh0,   // [3072][1024]
    const _Float16* __restrict__ Wi1,   // [3072][1024]
    const _Float16* __restrict__ Wh1,   // [3072][1024]
    const float* __restrict__ bias,     // [2][4][1024]
    float* __restrict__ h0f, float* __restrict__ h1f,       // fp32 masters
    _Float16* __restrict__ h0h, _Float16* __restrict__ h1h, // fp16 shadow x2
    _Float16* __restrict__ hn0,                             // layer0 out x2
    float* __restrict__ gi0, float* __restrict__ gi1,       // fp32 x2 each
    int* __restrict__ barctr)
{
    __shared__ _Float16 WL[16 * 48 * 72];   // 110,592 B (chunked [kc][48][72])
    __shared__ _Float16 AS[2][128][72];     //  36,864 B (A-chunk dbuf)

    const int bid = blockIdx.x;
    const int grp = bid >> 6;               // 0=D 1=A 2=C 3=B
    const int sl  = bid & 63;
    const int tid = threadIdx.x;
    const int lane = tid & 63, w = tid >> 6;
    const int m = lane & 15, q = lane >> 4;

    // ---- one-time: load this WG's weight slice into LDS ----
    {
        const _Float16* Wsrc; int K;
        if      (grp == 0) { Wsrc = Wi0; K = 512;  }
        else if (grp == 1) { Wsrc = Wh0; K = 1024; }
        else if (grp == 2) { Wsrc = Wi1; K = 1024; }
        else               { Wsrc = Wh1; K = 1024; }
        const bool isAB = (grp & 1);
        const int nchw = K / 64;
        for (int u = tid; u < nchw * 384; u += 256) {
            int kc = u / 384, rem = u % 384, c = rem >> 3, slot = rem & 7;
            int gr = isAB ? ((c >> 4) * 1024 + sl * 16 + (c & 15)) : (sl * 48 + c);
            *(u32x4*)&WL[(kc * 48 + c) * 72 + slot * 8] =
                *(const u32x4*)(Wsrc + (size_t)gr * K + kc * 64 + slot * 8);
        }
    }
    __syncthreads();

    // loop-invariant epilogue constants (A/B only)
    const int colG = sl * 16 + m;
    float br = 0.f, bz = 0.f, bi = 0.f, bh = 0.f;
    if (grp & 1) {
        const float* bb = bias + (grp == 3 ? 4 * H_ : 0);
        br = bb[colG]; bz = bb[H_ + colG];
        bi = bb[2 * H_ + colG]; bh = bb[3 * H_ + colG];
    }

    // staging map: 2 threads/row, 32 halves (64B) each
    const int srow = tid >> 1, spart = tid & 1;

    // barrier lines: 8 shard lines (1 KB apart) + master + epoch
    int* shard  = barctr + (bid & 7) * 256;
    int* master = barctr + 8 * 256;
    int* epoch  = barctr + 9 * 256;

    v4f acc[6];

    for (int k = 0; k < T_ + 3; ++k) {
        int t = k - grp + (grp == 0 ? 0 : (grp == 2 ? 0 : 0));  // placeholder
        // stage timestep: D:t=k  A:t=k-1  C:t=k-2  B:t=k-3
        t = (grp == 0) ? k : (grp == 1) ? k - 1 : (grp == 2) ? k - 2 : k - 3;
        const bool active = (t >= 0) && (t < T_);

        if (active) {
            const int pb = t & 1;           // ping-pong buffer for step-t data
            const int rb = pb ^ 1;          // buffer holding step-(t-1) data
            const _Float16* Abase; int ap, nch;
            if      (grp == 0) { Abase = x16 + (size_t)t * B_ * E_;  ap = E_; nch = 8;  }
            else if (grp == 1) { Abase = h0h + (size_t)rb * BH;      ap = H_; nch = 16; }
            else if (grp == 2) { Abase = hn0 + (size_t)pb * BH;      ap = H_; nch = 16; }
            else               { Abase = h1h + (size_t)rb * BH;      ap = H_; nch = 16; }

#pragma unroll
            for (int i = 0; i < 6; ++i) acc[i] = (v4f){0.f, 0.f, 0.f, 0.f};

            const _Float16* sp = Abase + (size_t)srow * ap + spart * 32;
            u32x4 rv0, rv1, rv2, rv3;
            // prologue: chunk 0
            rv0 = *(const u32x4*)(sp + 0);
            rv1 = *(const u32x4*)(sp + 8);
            rv2 = *(const u32x4*)(sp + 16);
            rv3 = *(const u32x4*)(sp + 24);
            {
                _Float16* d = &AS[0][srow][spart * 32];
                *(u32x4*)(d + 0) = rv0; *(u32x4*)(d + 8)  = rv1;
                *(u32x4*)(d + 16) = rv2; *(u32x4*)(d + 24) = rv3;
            }
            __syncthreads();

            int buf = 0;
            for (int kc = 0; kc < nch; ++kc) {
                const bool more = (kc + 1 < nch);
                if (more) {   // issue next chunk's loads early (T14)
                    const _Float16* p = sp + (kc + 1) * 64;
                    rv0 = *(const u32x4*)(p + 0);
                    rv1 = *(const u32x4*)(p + 8);
                    rv2 = *(const u32x4*)(p + 16);
                    rv3 = *(const u32x4*)(p + 24);
                }
                // MFMA on current chunk (LDS A x LDS W)
                const _Float16* wch = &WL[kc * 48 * 72];
#pragma unroll
                for (int s = 0; s < 2; ++s) {
                    const int ko = s * 32 + q * 8;
                    v8h a0 = *(const v8h*)&AS[buf][32 * w + m][ko];
                    v8h a1 = *(const v8h*)&AS[buf][32 * w + 16 + m][ko];
#pragma unroll
                    for (int g = 0; g < 3; ++g) {
                        v8h b = *(const v8h*)&wch[(g * 16 + m) * 72 + ko];
                        acc[g * 2 + 0] = __builtin_amdgcn_mfma_f32_16x16x32_f16(a0, b, acc[g * 2 + 0], 0, 0, 0);
                        acc[g * 2 + 1] = __builtin_amdgcn_mfma_f32_16x16x32_f16(a1, b, acc[g * 2 + 1], 0, 0, 0);
                    }
                }
                if (more) {   // write-late into the other buffer
                    _Float16* d = &AS[buf ^ 1][srow][spart * 32];
                    *(u32x4*)(d + 0) = rv0; *(u32x4*)(d + 8)  = rv1;
                    *(u32x4*)(d + 16) = rv2; *(u32x4*)(d + 24) = rv3;
                }
                __syncthreads();
                buf ^= 1;
            }

            // ---- epilogue ----
            if (grp == 0 || grp == 2) {
                // store raw GEMM -> gi (fp32, step-t buffer)
                float* gw = (grp == 0 ? gi0 : gi1) + (size_t)pb * GI;
                const int cbase = sl * 48;
#pragma unroll
                for (int cf = 0; cf < 3; ++cf)
#pragma unroll
                    for (int rf = 0; rf < 2; ++rf)
#pragma unroll
                        for (int r = 0; r < 4; ++r) {
                            int row = 32 * w + rf * 16 + q * 4 + r;
                            sc_store4(gw + (size_t)row * 3072 + cbase + cf * 16 + m,
                                      acc[cf * 2 + rf][r]);
                        }
            } else {
                const int bs_t = bs[t];
                const float* gr_ = (grp == 1 ? gi0 : gi1) + (size_t)pb * GI;
                float*      hf   = (grp == 1 ? h0f : h1f);
                _Float16*   hh_w = (grp == 1 ? h0h : h1h) + (size_t)pb * BH;
                _Float16*   hn0w = hn0 + (size_t)pb * BH;
#pragma unroll
                for (int rf = 0; rf < 2; ++rf)
#pragma unroll
                    for (int r = 0; r < 4; ++r) {
                        int row = 32 * w + rf * 16 + q * 4 + r;
                        size_t go = (size_t)row * 3072 + colG;
                        float gir = gr_[go];
                        float giz = gr_[go + 1024];
                        float gin = gr_[go + 2048];
                        size_t off = (size_t)row * H_ + colG;
                        float hprev = hf[off];
                        float rr = sigmoidf_(gir + acc[0 + rf][r] + br);
                        float zz = sigmoidf_(giz + acc[2 + rf][r] + bz);
                        float nn = tanhf_(gin + bi + rr * (acc[4 + rf][r] + bh));
                        float hnew = (1.0f - zz) * nn + zz * hprev;
                        bool act = row < bs_t;
                        float hsel = act ? hnew : hprev;
                        if (grp == 1)   // layer1 input: unmasked hn
                            sc_store2(hn0w + off, (unsigned)__builtin_bit_cast(unsigned short, (_Float16)hnew));
                        sc_store2(hh_w + off, (unsigned)__builtin_bit_cast(unsigned short, (_Float16)hsel));
                        if (act) hf[off] = hnew;   // private fp32 master: cached
                    }
            }
        }

        // ---- grid barrier: relaxed sharded arrivals, acquire-inv on exit ----
        if (k < T_ + 2) {
            __syncthreads();     // all waves drained (syncthreads waits vmcnt 0)
            if (tid == 0) {
                int old = __hip_atomic_fetch_add(shard, 1, __ATOMIC_RELAXED, __HIP_MEMORY_SCOPE_AGENT);
                if (old + 1 == 32 * (k + 1)) {
                    int mo = __hip_atomic_fetch_add(master, 1, __ATOMIC_RELAXED, __HIP_MEMORY_SCOPE_AGENT);
                    if (mo + 1 == 8 * (k + 1))
                        __hip_atomic_store(epoch, k + 1, __ATOMIC_RELEASE, __HIP_MEMORY_SCOPE_AGENT);
                }
                while (__hip_atomic_load(epoch, __ATOMIC_RELAXED, __HIP_MEMORY_SCOPE_AGENT) < k + 1)
                    __builtin_amdgcn_s_sleep(2);
                // acquire: invalidate L1/L2 so cached reads see sc1-written data
                (void)__hip_atomic_load(epoch, __ATOMIC_ACQUIRE, __HIP_MEMORY_SCOPE_AGENT);
            }
            __syncthreads();
        }
    }
}

// ---------------------------------------------------------------------------
// Preamble / epilogue helpers
// ---------------------------------------------------------------------------
__global__ void cvt_f32_f16(const float* __restrict__ s, _Float16* __restrict__ d, int n) {
    int i = (blockIdx.x * 256 + threadIdx.x) * 8;
    if (i >= n) return;
    float4 v0 = *(const float4*)(s + i);
    float4 v1 = *(const float4*)(s + i + 4);
    v8h o = { (_Float16)v0.x, (_Float16)v0.y, (_Float16)v0.z, (_Float16)v0.w,
              (_Float16)v1.x, (_Float16)v1.y, (_Float16)v1.z, (_Float16)v1.w };
    *(v8h*)(d + i) = o;
}

__global__ void prep_bias(const float* __restrict__ bi0, const float* __restrict__ bh0,
                          const float* __restrict__ bi1, const float* __restrict__ bh1,
                          float* __restrict__ bias) {
    int tid = blockIdx.x * 256 + threadIdx.x;   // 2048 threads
    int l = tid >> 10, j = tid & 1023;
    const float* bi = l ? bi1 : bi0;
    const float* bh = l ? bh1 : bh0;
    float* o = bias + l * 4 * H_;
    o[j]           = bi[j] + bh[j];
    o[H_ + j]      = bi[H_ + j] + bh[H_ + j];
    o[2 * H_ + j]  = bi[2 * H_ + j];
    o[3 * H_ + j]  = bh[2 * H_ + j];
}

__global__ void gather_out(const float* __restrict__ h0f, const float* __restrict__ h1f,
                           const int* __restrict__ unsorted, float* __restrict__ out) {
    int rowid = blockIdx.x;          // 256 = L*B
    int l = rowid >> 7, b = rowid & 127;
    int src = unsorted[b];
    const float* s = (l ? h1f : h0f) + (size_t)src * H_;
    float* o = out + (size_t)rowid * H_;
    int c = threadIdx.x * 4;
    *(float4*)(o + c) = *(const float4*)(s + c);
}

// ---------------------------------------------------------------------------
extern "C" void kernel_launch(void* const* d_in, const int* in_sizes, int n_in,
                              void* d_out, int out_size, void* d_ws, size_t ws_size,
                              hipStream_t stream) {
    const float* x    = (const float*)d_in[0];
    const float* Wi0f = (const float*)d_in[1];
    const float* Wh0f = (const float*)d_in[2];
    const float* bi0  = (const float*)d_in[3];
    const float* bh0  = (const float*)d_in[4];
    const float* Wi1f = (const float*)d_in[5];
    const float* Wh1f = (const float*)d_in[6];
    const float* bi1  = (const float*)d_in[7];
    const float* bh1  = (const float*)d_in[8];
    const int*  bs       = (const int*)d_in[9];
    const int*  unsorted = (const int*)d_in[10];
    float* out = (float*)d_out;

    char* ws = (char*)d_ws;
    size_t off = 0;
    auto alloc = [&](size_t bytes) -> char* {
        char* p = ws + off;
        off += (bytes + 255) & ~(size_t)255;
        return p;
    };
    _Float16* x16 = (_Float16*)alloc((size_t)T_ * B_ * E_ * 2);
    _Float16* Wi0 = (_Float16*)alloc((size_t)3 * H_ * E_ * 2);
    _Float16* Wh0 = (_Float16*)alloc((size_t)3 * H_ * H_ * 2);
    _Float16* Wi1 = (_Float16*)alloc((size_t)3 * H_ * H_ * 2);
    _Float16* Wh1 = (_Float16*)alloc((size_t)3 * H_ * H_ * 2);
    float*    bias = (float*)alloc(2 * 4 * H_ * 4);
    float*    gi0  = (float*)alloc((size_t)2 * GI * 4);   // written before read
    float*    gi1  = (float*)alloc((size_t)2 * GI * 4);
    char* zbase = ws + off;                  // zero-init block start
    float*    h0f = (float*)alloc((size_t)BH * 4);
    float*    h1f = (float*)alloc((size_t)BH * 4);
    _Float16* h0h = (_Float16*)alloc((size_t)2 * BH * 2);
    _Float16* h1h = (_Float16*)alloc((size_t)2 * BH * 2);
    _Float16* hn0 = (_Float16*)alloc((size_t)2 * BH * 2);
    int*      barctr = (int*)alloc(16 * 1024);
    size_t zbytes = (size_t)((ws + off) - zbase);

    (void)hipMemsetAsync(zbase, 0, zbytes, stream);

    cvt_f32_f16<<<(T_ * B_ * E_) / 2048, 256, 0, stream>>>(x, x16, T_ * B_ * E_);
    cvt_f32_f16<<<(3 * H_ * E_) / 2048, 256, 0, stream>>>(Wi0f, Wi0, 3 * H_ * E_);
    cvt_f32_f16<<<(3 * H_ * H_) / 2048, 256, 0, stream>>>(Wh0f, Wh0, 3 * H_ * H_);
    cvt_f32_f16<<<(3 * H_ * H_) / 2048, 256, 0, stream>>>(Wi1f, Wi1, 3 * H_ * H_);
    cvt_f32_f16<<<(3 * H_ * H_) / 2048, 256, 0, stream>>>(Wh1f, Wh1, 3 * H_ * H_);
    prep_bias<<<8, 256, 0, stream>>>(bi0, bh0, bi1, bh1, bias);

    // Persistent: 256 WGs, 1/CU (147.5 KiB LDS), all co-resident.
    gru_persist<<<256, 256, 0, stream>>>(bs, x16, Wi0, Wh0, Wi1, Wh1, bias,
                                         h0f, h1f, h0h, h1h, hn0, gi0, gi1, barctr);
    gather_out<<<256, 256, 0, stream>>>(h0f, h1f, unsorted, out);
}

// Round 7
// 4855.046 us; speedup vs baseline: 1.7362x; 1.2121x over previous
//
#include <hip/hip_runtime.h>
#include <cstdint>
#include <cstddef>

#define T_ 256
#define B_ 128
#define E_ 512
#define H_ 1024
#define BH (B_*H_)
#define GI (B_*3072)      // one gi buffer (fp32): 128 x 3072

typedef _Float16 v8h __attribute__((ext_vector_type(8)));
typedef float    v4f __attribute__((ext_vector_type(4)));
typedef unsigned int u32x4 __attribute__((ext_vector_type(4)));

__device__ __forceinline__ float sigmoidf_(float x) {
    return 1.0f / (1.0f + __expf(-x));
}
__device__ __forceinline__ float tanhf_(float x) {
    return 1.0f - 2.0f / (__expf(2.0f * x) + 1.0f);
}

// Cross-WG data is WRITTEN with L1/L2-bypassing stores (small volume), and
// READ with normal cached loads; read coherence comes from the acquire-inv
// at the barrier. Weights live in LDS, so the invalidate costs nothing.
__device__ __forceinline__ void sc_store2(void* p, unsigned v) {
    asm volatile("global_store_short %0, %1, off sc0 sc1" :: "v"(p), "v"(v) : "memory");
}
__device__ __forceinline__ void sc_store4(void* p, float v) {
    asm volatile("global_store_dword %0, %1, off sc0 sc1" :: "v"(p), "v"(v) : "memory");
}

// ---------------------------------------------------------------------------
// Persistent 4-stage pipelined GRU (R6 structure, R7: 4-deep chunk prefetch +
// register-resident fp32 h-master).
// Iteration k:
//   D (wg 0..63):    gi0[t=k]   = x[t] @ Wi0.T          (k <= T-1)
//   A (wg 64..127):  h0/hn0[t=k-1] from gi0[t] + h0@Wh0 (1 <= k <= T)
//   C (wg 128..191): gi1[t=k-2] = hn0[t] @ Wi1.T        (2 <= k <= T+1)
//   B (wg 192..255): h1[t=k-3] from gi1[t] + h1@Wh1     (3 <= k <= T+2)
// Per WG: 48 gate cols x K<=1024 weight slice in LDS. A-panel staged in
// 64-half chunks, double-buffered LDS + 4-deep register prefetch queue
// (chunk kc+4 issued at kc -> ~1000cyc latency slack over the post-inv
// MALL/HBM miss).
// ---------------------------------------------------------------------------
__global__ __launch_bounds__(256, 1) void gru_persist(
    const int* __restrict__ bs,
    const _Float16* __restrict__ x16,   // [T][B][E]
    const _Float16* __restrict__ Wi0,   // [3072][512]
    const _Float16* __restrict__ Wh0,   // [3072][1024]
    const _Float16* __restrict__ Wi1,   // [3072][1024]
    const _Float16* __restrict__ Wh1,   // [3072][1024]
    const float* __restrict__ bias,     // [2][4][1024]
    float* __restrict__ h0f, float* __restrict__ h1f,       // fp32 out (written once)
    _Float16* __restrict__ h0h, _Float16* __restrict__ h1h, // fp16 shadow x2
    _Float16* __restrict__ hn0,                             // layer0 out x2
    float* __restrict__ gi0, float* __restrict__ gi1,       // fp32 x2 each
    int* __restrict__ barctr)
{
    __shared__ _Float16 WL[16 * 48 * 72];   // 110,592 B (chunked [kc][48][72])
    __shared__ _Float16 AS[2][128][72];     //  36,864 B (A-chunk dbuf)

    const int bid = blockIdx.x;
    const int grp = bid >> 6;               // 0=D 1=A 2=C 3=B
    const int sl  = bid & 63;
    const int tid = threadIdx.x;
    const int lane = tid & 63, w = tid >> 6;
    const int m = lane & 15, q = lane >> 4;

    // ---- one-time: load this WG's weight slice into LDS ----
    {
        const _Float16* Wsrc; int K;
        if      (grp == 0) { Wsrc = Wi0; K = 512;  }
        else if (grp == 1) { Wsrc = Wh0; K = 1024; }
        else if (grp == 2) { Wsrc = Wi1; K = 1024; }
        else               { Wsrc = Wh1; K = 1024; }
        const bool isAB = (grp & 1);
        const int nchw = K / 64;
        for (int u = tid; u < nchw * 384; u += 256) {
            int kc = u / 384, rem = u % 384, c = rem >> 3, slot = rem & 7;
            int gr = isAB ? ((c >> 4) * 1024 + sl * 16 + (c & 15)) : (sl * 48 + c);
            *(u32x4*)&WL[(kc * 48 + c) * 72 + slot * 8] =
                *(const u32x4*)(Wsrc + (size_t)gr * K + kc * 64 + slot * 8);
        }
    }
    __syncthreads();

    // loop-invariant epilogue constants (A/B only)
    const int colG = sl * 16 + m;
    float br = 0.f, bz = 0.f, bi = 0.f, bh = 0.f;
    if (grp & 1) {
        const float* bb = bias + (grp == 3 ? 4 * H_ : 0);
        br = bb[colG]; bz = bb[H_ + colG];
        bi = bb[2 * H_ + colG]; bh = bb[3 * H_ + colG];
    }

    // register-resident fp32 h-master (A/B only): this thread owns
    // rows {32w + rf*16 + q*4 + r} x col colG forever.
    float hm[2][4];
#pragma unroll
    for (int rf = 0; rf < 2; ++rf)
#pragma unroll
        for (int r = 0; r < 4; ++r) hm[rf][r] = 0.f;

    // staging map: 2 threads/row, 32 halves (64B) each
    const int srow = tid >> 1, spart = tid & 1;

    // barrier lines: 8 shard lines (1 KB apart) + master + epoch
    int* shard  = barctr + (bid & 7) * 256;
    int* master = barctr + 8 * 256;
    int* epoch  = barctr + 9 * 256;

    v4f acc[6];
    u32x4 QA0, QA1, QA2, QA3, QB0, QB1, QB2, QB3;
    u32x4 QC0, QC1, QC2, QC3, QD0, QD1, QD2, QD3;

#define ISSUE(Qv, kcn) do { \
        const _Float16* p_ = sp + (size_t)(kcn) * 64; \
        Qv##0 = *(const u32x4*)(p_ + 0);  Qv##1 = *(const u32x4*)(p_ + 8); \
        Qv##2 = *(const u32x4*)(p_ + 16); Qv##3 = *(const u32x4*)(p_ + 24); \
    } while (0)
#define WRITEQ(Qv, dbuf) do { \
        _Float16* d_ = &AS[dbuf][srow][spart * 32]; \
        *(u32x4*)(d_ + 0) = Qv##0;  *(u32x4*)(d_ + 8)  = Qv##1; \
        *(u32x4*)(d_ + 16) = Qv##2; *(u32x4*)(d_ + 24) = Qv##3; \
    } while (0)
#define COMPUTE(BUF, KC) do { \
        const _Float16* wch_ = &WL[(KC) * 48 * 72]; \
        _Pragma("unroll") \
        for (int s = 0; s < 2; ++s) { \
            const int ko = s * 32 + q * 8; \
            v8h a0 = *(const v8h*)&AS[BUF][32 * w + m][ko]; \
            v8h a1 = *(const v8h*)&AS[BUF][32 * w + 16 + m][ko]; \
            _Pragma("unroll") \
            for (int g = 0; g < 3; ++g) { \
                v8h b = *(const v8h*)&wch_[(g * 16 + m) * 72 + ko]; \
                acc[g * 2 + 0] = __builtin_amdgcn_mfma_f32_16x16x32_f16(a0, b, acc[g * 2 + 0], 0, 0, 0); \
                acc[g * 2 + 1] = __builtin_amdgcn_mfma_f32_16x16x32_f16(a1, b, acc[g * 2 + 1], 0, 0, 0); \
            } \
        } \
    } while (0)
#define CHUNK_BODY(KC, QI, QW, BUF) do { \
        if ((KC) + 4 < nch) ISSUE(QI, (KC) + 4); \
        COMPUTE(BUF, KC); \
        if ((KC) + 1 < nch) WRITEQ(QW, (BUF) ^ 1); \
        __syncthreads(); \
    } while (0)

    for (int k = 0; k < T_ + 3; ++k) {
        // stage timestep: D:t=k  A:t=k-1  C:t=k-2  B:t=k-3
        const int t = (grp == 0) ? k : (grp == 1) ? k - 1 : (grp == 2) ? k - 2 : k - 3;
        const bool active = (t >= 0) && (t < T_);

        if (active) {
            const int pb = t & 1;           // ping-pong buffer for step-t data
            const int rb = pb ^ 1;          // buffer holding step-(t-1) data
            const _Float16* Abase; int ap, nch;
            if      (grp == 0) { Abase = x16 + (size_t)t * B_ * E_;  ap = E_; nch = 8;  }
            else if (grp == 1) { Abase = h0h + (size_t)rb * BH;      ap = H_; nch = 16; }
            else if (grp == 2) { Abase = hn0 + (size_t)pb * BH;      ap = H_; nch = 16; }
            else               { Abase = h1h + (size_t)rb * BH;      ap = H_; nch = 16; }

#pragma unroll
            for (int i = 0; i < 6; ++i) acc[i] = (v4f){0.f, 0.f, 0.f, 0.f};

            const _Float16* sp = Abase + (size_t)srow * ap + spart * 32;

            // pipeline fill: chunks 0..3 in flight; chunk 0 -> LDS buf 0
            ISSUE(QA, 0); ISSUE(QB, 1); ISSUE(QC, 2); ISSUE(QD, 3);
            WRITEQ(QA, 0);
            __syncthreads();

            for (int base = 0; base < nch; base += 4) {
                CHUNK_BODY(base + 0, QA, QB, 0);
                CHUNK_BODY(base + 1, QB, QC, 1);
                CHUNK_BODY(base + 2, QC, QD, 0);
                CHUNK_BODY(base + 3, QD, QA, 1);
            }

            // ---- epilogue ----
            if (grp == 0 || grp == 2) {
                // store raw GEMM -> gi (fp32, step-t buffer)
                float* gw = (grp == 0 ? gi0 : gi1) + (size_t)pb * GI;
                const int cbase = sl * 48;
#pragma unroll
                for (int cf = 0; cf < 3; ++cf)
#pragma unroll
                    for (int rf = 0; rf < 2; ++rf)
#pragma unroll
                        for (int r = 0; r < 4; ++r) {
                            int row = 32 * w + rf * 16 + q * 4 + r;
                            sc_store4(gw + (size_t)row * 3072 + cbase + cf * 16 + m,
                                      acc[cf * 2 + rf][r]);
                        }
            } else {
                const int bs_t = bs[t];
                const float* gr_ = (grp == 1 ? gi0 : gi1) + (size_t)pb * GI;
                _Float16*   hh_w = (grp == 1 ? h0h : h1h) + (size_t)pb * BH;
                _Float16*   hn0w = hn0 + (size_t)pb * BH;
#pragma unroll
                for (int rf = 0; rf < 2; ++rf)
#pragma unroll
                    for (int r = 0; r < 4; ++r) {
                        int row = 32 * w + rf * 16 + q * 4 + r;
                        size_t go = (size_t)row * 3072 + colG;
                        float gir = gr_[go];
                        float giz = gr_[go + 1024];
                        float gin = gr_[go + 2048];
                        size_t off = (size_t)row * H_ + colG;
                        float hprev = hm[rf][r];
                        float rr = sigmoidf_(gir + acc[0 + rf][r] + br);
                        float zz = sigmoidf_(giz + acc[2 + rf][r] + bz);
                        float nn = tanhf_(gin + bi + rr * (acc[4 + rf][r] + bh));
                        float hnew = (1.0f - zz) * nn + zz * hprev;
                        bool act = row < bs_t;
                        float hsel = act ? hnew : hprev;
                        if (grp == 1)   // layer1 input: unmasked hn
                            sc_store2(hn0w + off, (unsigned)__builtin_bit_cast(unsigned short, (_Float16)hnew));
                        sc_store2(hh_w + off, (unsigned)__builtin_bit_cast(unsigned short, (_Float16)hsel));
                        hm[rf][r] = hsel;          // fp32 master stays in regs
                    }
            }
        }

        // ---- grid barrier: relaxed sharded arrivals, acquire-inv on exit ----
        if (k < T_ + 2) {
            __syncthreads();     // all waves drained (syncthreads waits vmcnt 0)
            if (tid == 0) {
                int old = __hip_atomic_fetch_add(shard, 1, __ATOMIC_RELAXED, __HIP_MEMORY_SCOPE_AGENT);
                if (old + 1 == 32 * (k + 1)) {
                    int mo = __hip_atomic_fetch_add(master, 1, __ATOMIC_RELAXED, __HIP_MEMORY_SCOPE_AGENT);
                    if (mo + 1 == 8 * (k + 1))
                        __hip_atomic_store(epoch, k + 1, __ATOMIC_RELEASE, __HIP_MEMORY_SCOPE_AGENT);
                }
                while (__hip_atomic_load(epoch, __ATOMIC_RELAXED, __HIP_MEMORY_SCOPE_AGENT) < k + 1)
                    __builtin_amdgcn_s_sleep(2);
                // acquire: invalidate L1/L2 so cached reads see sc1-written data
                (void)__hip_atomic_load(epoch, __ATOMIC_ACQUIRE, __HIP_MEMORY_SCOPE_AGENT);
            }
            __syncthreads();
        }
    }

    // ---- final fp32 h writeback (once; kernel-end flush makes it visible) ----
    if (grp & 1) {
        float* hf = (grp == 1) ? h0f : h1f;
#pragma unroll
        for (int rf = 0; rf < 2; ++rf)
#pragma unroll
            for (int r = 0; r < 4; ++r) {
                int row = 32 * w + rf * 16 + q * 4 + r;
                hf[(size_t)row * H_ + colG] = hm[rf][r];
            }
    }
#undef ISSUE
#undef WRITEQ
#undef COMPUTE
#undef CHUNK_BODY
}

// ---------------------------------------------------------------------------
// Preamble / epilogue helpers
// ---------------------------------------------------------------------------
__global__ void cvt_f32_f16(const float* __restrict__ s, _Float16* __restrict__ d, int n) {
    int i = (blockIdx.x * 256 + threadIdx.x) * 8;
    if (i >= n) return;
    float4 v0 = *(const float4*)(s + i);
    float4 v1 = *(const float4*)(s + i + 4);
    v8h o = { (_Float16)v0.x, (_Float16)v0.y, (_Float16)v0.z, (_Float16)v0.w,
              (_Float16)v1.x, (_Float16)v1.y, (_Float16)v1.z, (_Float16)v1.w };
    *(v8h*)(d + i) = o;
}

__global__ void prep_bias(const float* __restrict__ bi0, const float* __restrict__ bh0,
                          const float* __restrict__ bi1, const float* __restrict__ bh1,
                          float* __restrict__ bias) {
    int tid = blockIdx.x * 256 + threadIdx.x;   // 2048 threads
    int l = tid >> 10, j = tid & 1023;
    const float* bi = l ? bi1 : bi0;
    const float* bh = l ? bh1 : bh0;
    float* o = bias + l * 4 * H_;
    o[j]           = bi[j] + bh[j];
    o[H_ + j]      = bi[H_ + j] + bh[H_ + j];
    o[2 * H_ + j]  = bi[2 * H_ + j];
    o[3 * H_ + j]  = bh[2 * H_ + j];
}

__global__ void gather_out(const float* __restrict__ h0f, const float* __restrict__ h1f,
                           const int* __restrict__ unsorted, float* __restrict__ out) {
    int rowid = blockIdx.x;          // 256 = L*B
    int l = rowid >> 7, b = rowid & 127;
    int src = unsorted[b];
    const float* s = (l ? h1f : h0f) + (size_t)src * H_;
    float* o = out + (size_t)rowid * H_;
    int c = threadIdx.x * 4;
    *(float4*)(o + c) = *(const float4*)(s + c);
}

// ---------------------------------------------------------------------------
extern "C" void kernel_launch(void* const* d_in, const int* in_sizes, int n_in,
                              void* d_out, int out_size, void* d_ws, size_t ws_size,
                              hipStream_t stream) {
    const float* x    = (const float*)d_in[0];
    const float* Wi0f = (const float*)d_in[1];
    const float* Wh0f = (const float*)d_in[2];
    const float* bi0  = (const float*)d_in[3];
    const float* bh0  = (const float*)d_in[4];
    const float* Wi1f = (const float*)d_in[5];
    const float* Wh1f = (const float*)d_in[6];
    const float* bi1  = (const float*)d_in[7];
    const float* bh1  = (const float*)d_in[8];
    const int*  bs       = (const int*)d_in[9];
    const int*  unsorted = (const int*)d_in[10];
    float* out = (float*)d_out;

    char* ws = (char*)d_ws;
    size_t off = 0;
    auto alloc = [&](size_t bytes) -> char* {
        char* p = ws + off;
        off += (bytes + 255) & ~(size_t)255;
        return p;
    };
    _Float16* x16 = (_Float16*)alloc((size_t)T_ * B_ * E_ * 2);
    _Float16* Wi0 = (_Float16*)alloc((size_t)3 * H_ * E_ * 2);
    _Float16* Wh0 = (_Float16*)alloc((size_t)3 * H_ * H_ * 2);
    _Float16* Wi1 = (_Float16*)alloc((size_t)3 * H_ * H_ * 2);
    _Float16* Wh1 = (_Float16*)alloc((size_t)3 * H_ * H_ * 2);
    float*    bias = (float*)alloc(2 * 4 * H_ * 4);
    float*    gi0  = (float*)alloc((size_t)2 * GI * 4);   // written before read
    float*    gi1  = (float*)alloc((size_t)2 * GI * 4);
    float*    h0f  = (float*)alloc((size_t)BH * 4);       // written once at end
    float*    h1f  = (float*)alloc((size_t)BH * 4);
    char* zbase = ws + off;                  // zero-init block start
    _Float16* h0h = (_Float16*)alloc((size_t)2 * BH * 2);
    _Float16* h1h = (_Float16*)alloc((size_t)2 * BH * 2);
    _Float16* hn0 = (_Float16*)alloc((size_t)2 * BH * 2);
    int*      barctr = (int*)alloc(16 * 1024);
    size_t zbytes = (size_t)((ws + off) - zbase);

    // fp16 shadows + barrier block must start at zero (h[-1] = 0).
    (void)hipMemsetAsync(zbase, 0, zbytes, stream);

    cvt_f32_f16<<<(T_ * B_ * E_) / 2048, 256, 0, stream>>>(x, x16, T_ * B_ * E_);
    cvt_f32_f16<<<(3 * H_ * E_) / 2048, 256, 0, stream>>>(Wi0f, Wi0, 3 * H_ * E_);
    cvt_f32_f16<<<(3 * H_ * H_) / 2048, 256, 0, stream>>>(Wh0f, Wh0, 3 * H_ * H_);
    cvt_f32_f16<<<(3 * H_ * H_) / 2048, 256, 0, stream>>>(Wi1f, Wi1, 3 * H_ * H_);
    cvt_f32_f16<<<(3 * H_ * H_) / 2048, 256, 0, stream>>>(Wh1f, Wh1, 3 * H_ * H_);
    prep_bias<<<8, 256, 0, stream>>>(bi0, bh0, bi1, bh1, bias);

    // Persistent: 256 WGs, 1/CU (147.5 KiB LDS), all co-resident.
    gru_persist<<<256, 256, 0, stream>>>(bs, x16, Wi0, Wh0, Wi1, Wh1, bias,
                                         h0f, h1f, h0h, h1h, hn0, gi0, gi1, barctr);
    gather_out<<<256, 256, 0, stream>>>(h0f, h1f, unsorted, out);
}

// Round 8
// 4793.551 us; speedup vs baseline: 1.7585x; 1.0128x over previous
//
#include <hip/hip_runtime.h>
#include <cstdint>
#include <cstddef>

#define T_ 256
#define B_ 128
#define E_ 512
#define H_ 1024
#define BH (B_*H_)
#define GI (B_*3072)      // gi0 buffer (fp32): 128 x 3072
#define GATHER_BID 64     // barrier gatherer: an A-stage WG (has slack)

typedef _Float16 v8h __attribute__((ext_vector_type(8)));
typedef float    v4f __attribute__((ext_vector_type(4)));
typedef unsigned int u32x4 __attribute__((ext_vector_type(4)));

__device__ __forceinline__ float sigmoidf_(float x) {
    return 1.0f / (1.0f + __expf(-x));
}
__device__ __forceinline__ float tanhf_(float x) {
    return 1.0f - 2.0f / (__expf(2.0f * x) + 1.0f);
}

// Cross-WG mutable data: WRITTEN with L2-bypassing stores (lands in MALL),
// READ with normal cached loads after the barrier's acquire-inv.
__device__ __forceinline__ void sc_store2(void* p, unsigned v) {
    asm volatile("global_store_short %0, %1, off sc0 sc1" :: "v"(p), "v"(v) : "memory");
}
__device__ __forceinline__ void sc_store4(void* p, float v) {
    asm volatile("global_store_dword %0, %1, off sc0 sc1" :: "v"(p), "v"(v) : "memory");
}

// ---------------------------------------------------------------------------
// Persistent 3-stage pipelined GRU.
// Round k (k = 0..T+1):
//   D (bid 0..63):    gi0[t=k]   = x[t] @ Wi0.T   (k<=T-1). x is immutable ->
//                     GEMM runs BEFORE the epoch wait (fully barrier-overlapped);
//                     only the gi0 store is gated (ping-pong protection).
//   A (bid 64..127):  h0/hn0[t=k-1] from gi0[t] + h0@Wh0, K=1024 (1<=k<=T)
//   B (bid 128..255): h1[t=k-2] full layer1: concat-K GEMM over
//                     [hn0[t] (K=1024) | h1[t-1] (K=1024)]  (2<=k<=T+1);
//                     NO gi1 intermediate. n-gate input/hidden parts kept in
//                     separate accumulators (accX / accH).
// Weights live in LDS per WG (<=110 KB) -> the barrier's L2 invalidate is
// cheap. fp32 h-masters live in registers. Barrier: per-WG flag stores +
// one gatherer publishes an epoch word (no RMW contention).
// ---------------------------------------------------------------------------
__global__ __launch_bounds__(256, 1) void gru_persist(
    const int* __restrict__ bs,
    const _Float16* __restrict__ x16,   // [T][B][E]
    const _Float16* __restrict__ Wi0,   // [3072][512]
    const _Float16* __restrict__ Wh0,   // [3072][1024]
    const _Float16* __restrict__ Wi1,   // [3072][1024]
    const _Float16* __restrict__ Wh1,   // [3072][1024]
    const float* __restrict__ bias,     // [2][4][1024]
    float* __restrict__ h0f, float* __restrict__ h1f,       // fp32 out (final)
    _Float16* __restrict__ h0h, _Float16* __restrict__ h1h, // fp16 shadow x2
    _Float16* __restrict__ hn0,                             // layer0 out x2
    float* __restrict__ gi0,                                // fp32 x2
    int* __restrict__ flags,            // [256] per-WG round counters
    int* __restrict__ epoch)            // single epoch word
{
    __shared__ _Float16 WL[55296];          // 110,592 B weight slice
    __shared__ _Float16 AS[2][128][72];     //  36,864 B A-chunk dbuf

    const int bid = blockIdx.x;
    const int tid = threadIdx.x;
    const int lane = tid & 63, w = tid >> 6;
    const int m = lane & 15, q = lane >> 4;
    const int srow = tid >> 1, spart = tid & 1;
    const int stage = (bid < 64) ? 0 : (bid < 128) ? 1 : 2;
    const int sl = (stage == 0) ? bid : (stage == 1) ? bid - 64 : bid - 128;

    // ---- one-time: weight slice -> LDS ----
    if (stage == 0) {          // D: Wi0, 48 contiguous gate cols, 8 chunks
        for (int u = tid; u < 8 * 384; u += 256) {
            int kc = u / 384, rem = u % 384, c = rem >> 3, slot = rem & 7;
            int gr = sl * 48 + c;
            *(u32x4*)&WL[(kc * 48 + c) * 72 + slot * 8] =
                *(const u32x4*)(Wi0 + (size_t)gr * E_ + kc * 64 + slot * 8);
        }
    } else if (stage == 1) {   // A: Wh0, 48 cols grouped [r16|z16|n16], 16 chunks
        for (int u = tid; u < 16 * 384; u += 256) {
            int kc = u / 384, rem = u % 384, c = rem >> 3, slot = rem & 7;
            int gr = (c >> 4) * 1024 + sl * 16 + (c & 15);
            *(u32x4*)&WL[(kc * 48 + c) * 72 + slot * 8] =
                *(const u32x4*)(Wh0 + (size_t)gr * H_ + kc * 64 + slot * 8);
        }
    } else {                   // B: Wi1 (kc<16) ++ Wh1, 24 cols [r8|z8|n8], 32 chunks
        for (int u = tid; u < 32 * 192; u += 256) {
            int kc = u / 192, rem = u % 192, c = rem >> 3, slot = rem & 7;
            int gr = (c >> 3) * 1024 + sl * 8 + (c & 7);
            const _Float16* src = (kc < 16) ? (Wi1 + (size_t)gr * H_ + kc * 64)
                                            : (Wh1 + (size_t)gr * H_ + (kc - 16) * 64);
            *(u32x4*)&WL[(kc * 24 + c) * 72 + slot * 8] = *(const u32x4*)(src + slot * 8);
        }
    }
    __syncthreads();

    // ---- loop-invariant epilogue constants ----
    float br = 0.f, bz = 0.f, bi = 0.f, bh = 0.f;
    int colE = 0;                         // epilogue column
    if (stage == 1) {
        colE = sl * 16 + m;
        br = bias[colE]; bz = bias[H_ + colE];
        bi = bias[2 * H_ + colE]; bh = bias[3 * H_ + colE];
    } else if (stage == 2) {
        colE = sl * 8 + (m & 7);
        const float* bb = bias + 4 * H_;
        br = bb[colE]; bz = bb[H_ + colE];
        bi = bb[2 * H_ + colE]; bh = bb[3 * H_ + colE];
    }
    float hm[2][4];                       // register fp32 h-master (A/B)
#pragma unroll
    for (int rf = 0; rf < 2; ++rf)
#pragma unroll
        for (int r = 0; r < 4; ++r) hm[rf][r] = 0.f;

    v4f acc[6];
    u32x4 QA0, QA1, QA2, QA3, QB0, QB1, QB2, QB3;
    u32x4 QC0, QC1, QC2, QC3, QD0, QD1, QD2, QD3;

#define ISSUE(Qv, kcn) do { \
        const _Float16* p_ = sp + (size_t)(kcn) * 64; \
        Qv##0 = *(const u32x4*)(p_ + 0);  Qv##1 = *(const u32x4*)(p_ + 8); \
        Qv##2 = *(const u32x4*)(p_ + 16); Qv##3 = *(const u32x4*)(p_ + 24); \
    } while (0)
#define WRITEQ(Qv, dbuf) do { \
        _Float16* d_ = &AS[dbuf][srow][spart * 32]; \
        *(u32x4*)(d_ + 0) = Qv##0;  *(u32x4*)(d_ + 8)  = Qv##1; \
        *(u32x4*)(d_ + 16) = Qv##2; *(u32x4*)(d_ + 24) = Qv##3; \
    } while (0)
    // D/A: 3 col-frags of 16 (acc[cf*2+rf])
#define COMPUTE3(BUF, KC) do { \
        const _Float16* wch_ = &WL[(KC) * 48 * 72]; \
        _Pragma("unroll") \
        for (int s = 0; s < 2; ++s) { \
            const int ko = s * 32 + q * 8; \
            v8h a0 = *(const v8h*)&AS[BUF][32 * w + m][ko]; \
            v8h a1 = *(const v8h*)&AS[BUF][32 * w + 16 + m][ko]; \
            _Pragma("unroll") \
            for (int g = 0; g < 3; ++g) { \
                v8h b = *(const v8h*)&wch_[(g * 16 + m) * 72 + ko]; \
                acc[g * 2 + 0] = __builtin_amdgcn_mfma_f32_16x16x32_f16(a0, b, acc[g * 2 + 0], 0, 0, 0); \
                acc[g * 2 + 1] = __builtin_amdgcn_mfma_f32_16x16x32_f16(a1, b, acc[g * 2 + 1], 0, 0, 0); \
            } \
        } \
    } while (0)
#define CHUNK3(KC, QI, QW, BUF) do { \
        if ((KC) + 4 < nch) ISSUE(QI, (KC) + 4); \
        COMPUTE3(BUF, KC); \
        if ((KC) + 1 < nch) WRITEQ(QW, (BUF) ^ 1); \
        __syncthreads(); \
    } while (0)
    // B: overlapped frags: cf0 = WL rows 0..15 [r|z], cf1 = rows 8..23 [z|n]
    // acc[0..1] = cf0 (full sum), ACN = cf1 acc pair (accX: acc[2..3], accH: acc[4..5])
#define COMPUTE2(BUF, KC, ANB) do { \
        const _Float16* wch_ = &WL[(KC) * 24 * 72]; \
        _Pragma("unroll") \
        for (int s = 0; s < 2; ++s) { \
            const int ko = s * 32 + q * 8; \
            v8h a0 = *(const v8h*)&AS[BUF][32 * w + m][ko]; \
            v8h a1 = *(const v8h*)&AS[BUF][32 * w + 16 + m][ko]; \
            v8h b0 = *(const v8h*)&wch_[(m) * 72 + ko]; \
            v8h b1 = *(const v8h*)&wch_[(8 + m) * 72 + ko]; \
            acc[0] = __builtin_amdgcn_mfma_f32_16x16x32_f16(a0, b0, acc[0], 0, 0, 0); \
            acc[1] = __builtin_amdgcn_mfma_f32_16x16x32_f16(a1, b0, acc[1], 0, 0, 0); \
            acc[(ANB) + 0] = __builtin_amdgcn_mfma_f32_16x16x32_f16(a0, b1, acc[(ANB) + 0], 0, 0, 0); \
            acc[(ANB) + 1] = __builtin_amdgcn_mfma_f32_16x16x32_f16(a1, b1, acc[(ANB) + 1], 0, 0, 0); \
        } \
    } while (0)
#define CHUNK2(KC, QI, QW, BUF, KB, ANB) do { \
        if ((KC) + 4 < 16) ISSUE(QI, (KC) + 4); \
        COMPUTE2((KC) + (KB), BUF, ANB); \
    } while (0)
    // (note: COMPUTE2 args order fixed below at use)
#define SUBLOOP2(KB, ANB) do { \
        ISSUE(QA, 0); ISSUE(QB, 1); ISSUE(QC, 2); ISSUE(QD, 3); \
        WRITEQ(QA, 0); \
        __syncthreads(); \
        for (int base = 0; base < 16; base += 4) { \
            if (base + 4 < 16) ISSUE(QA, base + 4); \
            COMPUTE2(0, (KB) + base + 0, ANB); \
            if (base + 1 < 16) WRITEQ(QB, 1); \
            __syncthreads(); \
            if (base + 5 < 16) ISSUE(QB, base + 5); \
            COMPUTE2(1, (KB) + base + 1, ANB); \
            if (base + 2 < 16) WRITEQ(QC, 0); \
            __syncthreads(); \
            if (base + 6 < 16) ISSUE(QC, base + 6); \
            COMPUTE2(0, (KB) + base + 2, ANB); \
            if (base + 3 < 16) WRITEQ(QD, 1); \
            __syncthreads(); \
            if (base + 7 < 16) ISSUE(QD, base + 7); \
            COMPUTE2(1, (KB) + base + 3, ANB); \
            if (base + 4 < 16) WRITEQ(QA, 0); \
            __syncthreads(); \
        } \
    } while (0)

    // wait for epoch >= k; optional acquire-inv (L1/L2 invalidate)
#define WAIT_EPOCH(KV, DO_INV) do { \
        if (tid == 0) { \
            while (__hip_atomic_load(epoch, __ATOMIC_RELAXED, __HIP_MEMORY_SCOPE_AGENT) < (KV)) \
                __builtin_amdgcn_s_sleep(1); \
            if (DO_INV) (void)__hip_atomic_load(epoch, __ATOMIC_ACQUIRE, __HIP_MEMORY_SCOPE_AGENT); \
        } \
        __syncthreads(); \
    } while (0)
    // flag own round done; gatherer publishes epoch
#define DO_BARRIER(KV) do { \
        __syncthreads(); \
        if (tid == 0) \
            __hip_atomic_store(&flags[bid], (KV) + 1, __ATOMIC_RELEASE, __HIP_MEMORY_SCOPE_AGENT); \
        if (bid == GATHER_BID && tid < 64) { \
            const int tgt = (KV) + 1; \
            for (;;) { \
                int f0 = __hip_atomic_load(&flags[tid],       __ATOMIC_RELAXED, __HIP_MEMORY_SCOPE_AGENT); \
                int f1 = __hip_atomic_load(&flags[tid + 64],  __ATOMIC_RELAXED, __HIP_MEMORY_SCOPE_AGENT); \
                int f2 = __hip_atomic_load(&flags[tid + 128], __ATOMIC_RELAXED, __HIP_MEMORY_SCOPE_AGENT); \
                int f3 = __hip_atomic_load(&flags[tid + 192], __ATOMIC_RELAXED, __HIP_MEMORY_SCOPE_AGENT); \
                bool ok = (f0 >= tgt) && (f1 >= tgt) && (f2 >= tgt) && (f3 >= tgt); \
                if (__all(ok)) break; \
                __builtin_amdgcn_s_sleep(1); \
            } \
            if (tid == 0) \
                __hip_atomic_store(epoch, (KV) + 1, __ATOMIC_RELEASE, __HIP_MEMORY_SCOPE_AGENT); \
        } \
    } while (0)

    for (int k = 0; k < T_ + 2; ++k) {
        if (stage == 0) {
            // ================= D: gi0[t=k] = x[t] @ Wi0.T =================
            const bool active = (k < T_);
            if (active) {
                const int t = k;
#pragma unroll
                for (int i = 0; i < 6; ++i) acc[i] = (v4f){0.f, 0.f, 0.f, 0.f};
                const _Float16* sp = x16 + (size_t)t * B_ * E_ + (size_t)srow * E_ + spart * 32;
                const int nch = 8;
                ISSUE(QA, 0); ISSUE(QB, 1); ISSUE(QC, 2); ISSUE(QD, 3);
                WRITEQ(QA, 0);
                __syncthreads();
                CHUNK3(0, QA, QB, 0); CHUNK3(1, QB, QC, 1);
                CHUNK3(2, QC, QD, 0); CHUNK3(3, QD, QA, 1);
                CHUNK3(4, QA, QB, 0); CHUNK3(5, QB, QC, 1);
                CHUNK3(6, QC, QD, 0); CHUNK3(7, QD, QA, 1);
                // store gated by epoch only (ping-pong protection); no inv needed
                WAIT_EPOCH(k, false);
                float* gw = gi0 + (size_t)(t & 1) * GI;
                const int cbase = sl * 48;
#pragma unroll
                for (int cf = 0; cf < 3; ++cf)
#pragma unroll
                    for (int rf = 0; rf < 2; ++rf)
#pragma unroll
                        for (int r = 0; r < 4; ++r) {
                            int row = 32 * w + rf * 16 + q * 4 + r;
                            sc_store4(gw + (size_t)row * 3072 + cbase + cf * 16 + m,
                                      acc[cf * 2 + rf][r]);
                        }
            }
        } else if (stage == 1) {
            // ====== A: h0/hn0[t=k-1] from gi0[t] + h0[t-1]@Wh0 ======
            const bool active = (k >= 1) && (k <= T_);
            if (active) {
                const int t = k - 1;
                WAIT_EPOCH(k, true);
                const int bs_t = bs[t];
                const int pb = t & 1, rb = pb ^ 1;
#pragma unroll
                for (int i = 0; i < 6; ++i) acc[i] = (v4f){0.f, 0.f, 0.f, 0.f};
                const _Float16* sp = h0h + (size_t)rb * BH + (size_t)srow * H_ + spart * 32;
                const int nch = 16;
                ISSUE(QA, 0); ISSUE(QB, 1); ISSUE(QC, 2); ISSUE(QD, 3);
                WRITEQ(QA, 0);
                __syncthreads();
                for (int base = 0; base < 16; base += 4) {
                    CHUNK3(base + 0, QA, QB, 0); CHUNK3(base + 1, QB, QC, 1);
                    CHUNK3(base + 2, QC, QD, 0); CHUNK3(base + 3, QD, QA, 1);
                }
                // epilogue
                const float* gr_ = gi0 + (size_t)pb * GI;
                _Float16* hh_w = h0h + (size_t)pb * BH;
                _Float16* hn0w = hn0 + (size_t)pb * BH;
#pragma unroll
                for (int rf = 0; rf < 2; ++rf)
#pragma unroll
                    for (int r = 0; r < 4; ++r) {
                        int row = 32 * w + rf * 16 + q * 4 + r;
                        size_t go = (size_t)row * 3072 + colE;
                        float gir = gr_[go];
                        float giz = gr_[go + 1024];
                        float gin = gr_[go + 2048];
                        size_t off = (size_t)row * H_ + colE;
                        float hprev = hm[rf][r];
                        float rr = sigmoidf_(gir + acc[0 + rf][r] + br);
                        float zz = sigmoidf_(giz + acc[2 + rf][r] + bz);
                        float nn = tanhf_(gin + bi + rr * (acc[4 + rf][r] + bh));
                        float hnew = (1.0f - zz) * nn + zz * hprev;
                        bool act = row < bs_t;
                        float hsel = act ? hnew : hprev;
                        sc_store2(hn0w + off, (unsigned)__builtin_bit_cast(unsigned short, (_Float16)hnew));
                        sc_store2(hh_w + off, (unsigned)__builtin_bit_cast(unsigned short, (_Float16)hsel));
                        hm[rf][r] = hsel;
                    }
            } else if (bid == GATHER_BID) {
                WAIT_EPOCH(k, false);   // keep gatherer in step even when idle
            }
        } else {
            // ====== B: h1[t=k-2] = layer1(hn0[t], h1[t-1]); concat K=2048 ======
            const bool active = (k >= 2);
            if (active) {
                const int t = k - 2;
                WAIT_EPOCH(k, true);
                const int bs_t = bs[t];
                const int pb = t & 1, rb = pb ^ 1;
#pragma unroll
                for (int i = 0; i < 6; ++i) acc[i] = (v4f){0.f, 0.f, 0.f, 0.f};
                {   // sub-GEMM 1: hn0[t] @ Wi1 (WL chunks 0..15) -> accX = acc[2..3]
                    const _Float16* sp = hn0 + (size_t)pb * BH + (size_t)srow * H_ + spart * 32;
                    SUBLOOP2(0, 2);
                }
                {   // sub-GEMM 2: h1[t-1] @ Wh1 (WL chunks 16..31) -> accH = acc[4..5]
                    const _Float16* sp = h1h + (size_t)rb * BH + (size_t)srow * H_ + spart * 32;
                    SUBLOOP2(16, 4);
                }
                // epilogue: lane m<8 owns hidden col sl*8+m; z/in/hn via shfl(+8)
                _Float16* hh_w = h1h + (size_t)pb * BH;
#pragma unroll
                for (int rf = 0; rf < 2; ++rf)
#pragma unroll
                    for (int r = 0; r < 4; ++r) {
                        int row = 32 * w + rf * 16 + q * 4 + r;
                        float zz_s = __shfl_xor(acc[0 + rf][r], 8);
                        float inx  = __shfl_xor(acc[2 + rf][r], 8);
                        float hnh  = __shfl_xor(acc[4 + rf][r], 8);
                        float hprev = hm[rf][r];
                        float rr = sigmoidf_(acc[0 + rf][r] + br);
                        float zz = sigmoidf_(zz_s + bz);
                        float nn = tanhf_(inx + bi + rr * (hnh + bh));
                        float hnew = (1.0f - zz) * nn + zz * hprev;
                        bool act = row < bs_t;
                        float hsel = act ? hnew : hprev;
                        if (m < 8) {
                            size_t off = (size_t)row * H_ + colE;
                            sc_store2(hh_w + off, (unsigned)__builtin_bit_cast(unsigned short, (_Float16)hsel));
                        }
                        hm[rf][r] = hsel;
                    }
            }
        }

        // ---- barrier (skip after final round) ----
        if (k < T_ + 1) DO_BARRIER(k);
    }

    // ---- final fp32 writeback ----
    if (stage == 1) {
#pragma unroll
        for (int rf = 0; rf < 2; ++rf)
#pragma unroll
            for (int r = 0; r < 4; ++r) {
                int row = 32 * w + rf * 16 + q * 4 + r;
                h0f[(size_t)row * H_ + colE] = hm[rf][r];
            }
    } else if (stage == 2 && m < 8) {
#pragma unroll
        for (int rf = 0; rf < 2; ++rf)
#pragma unroll
            for (int r = 0; r < 4; ++r) {
                int row = 32 * w + rf * 16 + q * 4 + r;
                h1f[(size_t)row * H_ + colE] = hm[rf][r];
            }
    }
}

// ---------------------------------------------------------------------------
// Preamble / epilogue helpers
// ---------------------------------------------------------------------------
__global__ void cvt_f32_f16(const float* __restrict__ s, _Float16* __restrict__ d, int n) {
    int i = (blockIdx.x * 256 + threadIdx.x) * 8;
    if (i >= n) return;
    float4 v0 = *(const float4*)(s + i);
    float4 v1 = *(const float4*)(s + i + 4);
    v8h o = { (_Float16)v0.x, (_Float16)v0.y, (_Float16)v0.z, (_Float16)v0.w,
              (_Float16)v1.x, (_Float16)v1.y, (_Float16)v1.z, (_Float16)v1.w };
    *(v8h*)(d + i) = o;
}

__global__ void prep_bias(const float* __restrict__ bi0, const float* __restrict__ bh0,
                          const float* __restrict__ bi1, const float* __restrict__ bh1,
                          float* __restrict__ bias) {
    int tid = blockIdx.x * 256 + threadIdx.x;   // 2048 threads
    int l = tid >> 10, j = tid & 1023;
    const float* bi = l ? bi1 : bi0;
    const float* bh = l ? bh1 : bh0;
    float* o = bias + l * 4 * H_;
    o[j]           = bi[j] + bh[j];
    o[H_ + j]      = bi[H_ + j] + bh[H_ + j];
    o[2 * H_ + j]  = bi[2 * H_ + j];
    o[3 * H_ + j]  = bh[2 * H_ + j];
}

__global__ void gather_out(const float* __restrict__ h0f, const float* __restrict__ h1f,
                           const int* __restrict__ unsorted, float* __restrict__ out) {
    int rowid = blockIdx.x;          // 256 = L*B
    int l = rowid >> 7, b = rowid & 127;
    int src = unsorted[b];
    const float* s = (l ? h1f : h0f) + (size_t)src * H_;
    float* o = out + (size_t)rowid * H_;
    int c = threadIdx.x * 4;
    *(float4*)(o + c) = *(const float4*)(s + c);
}

// ---------------------------------------------------------------------------
extern "C" void kernel_launch(void* const* d_in, const int* in_sizes, int n_in,
                              void* d_out, int out_size, void* d_ws, size_t ws_size,
                              hipStream_t stream) {
    const float* x    = (const float*)d_in[0];
    const float* Wi0f = (const float*)d_in[1];
    const float* Wh0f = (const float*)d_in[2];
    const float* bi0  = (const float*)d_in[3];
    const float* bh0  = (const float*)d_in[4];
    const float* Wi1f = (const float*)d_in[5];
    const float* Wh1f = (const float*)d_in[6];
    const float* bi1  = (const float*)d_in[7];
    const float* bh1  = (const float*)d_in[8];
    const int*  bs       = (const int*)d_in[9];
    const int*  unsorted = (const int*)d_in[10];
    float* out = (float*)d_out;

    char* ws = (char*)d_ws;
    size_t off = 0;
    auto alloc = [&](size_t bytes) -> char* {
        char* p = ws + off;
        off += (bytes + 255) & ~(size_t)255;
        return p;
    };
    _Float16* x16 = (_Float16*)alloc((size_t)T_ * B_ * E_ * 2);
    _Float16* Wi0 = (_Float16*)alloc((size_t)3 * H_ * E_ * 2);
    _Float16* Wh0 = (_Float16*)alloc((size_t)3 * H_ * H_ * 2);
    _Float16* Wi1 = (_Float16*)alloc((size_t)3 * H_ * H_ * 2);
    _Float16* Wh1 = (_Float16*)alloc((size_t)3 * H_ * H_ * 2);
    float*    bias = (float*)alloc(2 * 4 * H_ * 4);
    float*    gi0  = (float*)alloc((size_t)2 * GI * 4);   // written before read
    float*    h0f  = (float*)alloc((size_t)BH * 4);       // written once at end
    float*    h1f  = (float*)alloc((size_t)BH * 4);
    char* zbase = ws + off;                  // zero-init block start
    _Float16* h0h = (_Float16*)alloc((size_t)2 * BH * 2);
    _Float16* h1h = (_Float16*)alloc((size_t)2 * BH * 2);
    _Float16* hn0 = (_Float16*)alloc((size_t)2 * BH * 2);
    int*      flags = (int*)alloc(1024);     // 256 flags
    int*      epoch = (int*)alloc(256);
    size_t zbytes = (size_t)((ws + off) - zbase);

    // fp16 shadows + flags/epoch must start at zero (h[-1] = 0, epoch 0).
    (void)hipMemsetAsync(zbase, 0, zbytes, stream);

    cvt_f32_f16<<<(T_ * B_ * E_) / 2048, 256, 0, stream>>>(x, x16, T_ * B_ * E_);
    cvt_f32_f16<<<(3 * H_ * E_) / 2048, 256, 0, stream>>>(Wi0f, Wi0, 3 * H_ * E_);
    cvt_f32_f16<<<(3 * H_ * H_) / 2048, 256, 0, stream>>>(Wh0f, Wh0, 3 * H_ * H_);
    cvt_f32_f16<<<(3 * H_ * H_) / 2048, 256, 0, stream>>>(Wi1f, Wi1, 3 * H_ * H_);
    cvt_f32_f16<<<(3 * H_ * H_) / 2048, 256, 0, stream>>>(Wh1f, Wh1, 3 * H_ * H_);
    prep_bias<<<8, 256, 0, stream>>>(bi0, bh0, bi1, bh1, bias);

    // Persistent: 256 WGs, 1/CU (147.5 KiB LDS), all co-resident.
    gru_persist<<<256, 256, 0, stream>>>(bs, x16, Wi0, Wh0, Wi1, Wh1, bias,
                                         h0f, h1f, h0h, h1h, hn0, gi0, flags, epoch);
    gather_out<<<256, 256, 0, stream>>>(h0f, h1f, unsorted, out);
}